// Round 4
// baseline (522.854 us; speedup 1.0000x reference)
//
#include <hip/hip_runtime.h>
#include <stdint.h>

typedef __attribute__((ext_vector_type(4))) float f32x4;
typedef __attribute__((ext_vector_type(8))) short bf16x8;
typedef __attribute__((ext_vector_type(2))) unsigned int u32x2;

#define B_SZ   32
#define L_AUD  441000
#define PAD_A  1024
#define LP     443048          // L_AUD + 2*PAD_A
#define T_FR   862
#define J_TOT  27584           // B_SZ * T_FR
#define JPAD   27648           // 108 * 256
#define F_BINS 1025
#define NFFT   2048
#define NB     64
#define FPAD   1152            // 9 * 128
#define NT_J   108             // 27648 / 256
#define NT_F   9
#define NWG    (NT_J * NT_F)   // 972
#define ROWB   886096          // LP * 2 bytes per xbp row

#define XBP_OFF   0
#define XBP_BYTES (B_SZ * LP * 2)             // 28,355,072
#define WBT_OFF   XBP_BYTES
#define WBT_BYTES (NT_F * 32 * 2 * 16384)     // 9,437,184
#define GB_OFF    (WBT_OFF + WBT_BYTES)
#define GB_BYTES  (NB * FPAD * 2)             // 147,456
#define WS_NEED   (GB_OFF + GB_BYTES)         // 37,939,712
#define SLAB_OFF  WS_NEED
#define SLAB_BYTES ((size_t)NT_F * NB * JPAD * 4)   // 63,700,992
#define WS_BIG    (SLAB_OFF + SLAB_BYTES)     // 101,640,704

__device__ __forceinline__ uint16_t f2bf(float f) {
  union { float f; uint32_t u; } c; c.f = f;
  uint32_t r = c.u + 0x7FFFu + ((c.u >> 16) & 1u);
  return (uint16_t)(r >> 16);
}

__device__ __forceinline__ f32x4 mfma16(bf16x8 a, bf16x8 b, f32x4 c) {
  return __builtin_amdgcn_mfma_f32_16x16x32_bf16(a, b, c, 0, 0, 0);
}

#define GLD16(g, l) __builtin_amdgcn_global_load_lds( \
    (__attribute__((address_space(1))) void*)(g),     \
    (__attribute__((address_space(3))) void*)(l), 16, 0, 0)

// ---- prep: reflect-padded bf16 audio ------------------------------------
__global__ __launch_bounds__(256) void build_xbp(const float* __restrict__ x,
                                                 uint16_t* __restrict__ xbp) {
  int i = blockIdx.x * 256 + threadIdx.x;
  int b = i / LP;
  int p = i - b * LP;
  int s = p - PAD_A;
  s = s < 0 ? -s : s;
  s = s >= L_AUD ? (2 * L_AUD - 2 - s) : s;
  xbp[i] = f2bf(x[b * L_AUD + s]);
}

// ---- prep: W blobs (pre-swizzled linear staging order) -------------------
__global__ __launch_bounds__(256) void build_wbt(const float* __restrict__ wsin,
                                                 const float* __restrict__ wcos,
                                                 char* __restrict__ wbt) {
  int idx = blockIdx.x * 256 + threadIdx.x;
  int e = idx & 8191;
  int blob = idx >> 13;
  int half = blob & 1;
  int kkt = (blob >> 1) & 31;
  int fb = blob >> 6;
  int lr = e >> 6;
  int b_in_row = (e << 1) & 127;
  int kl = (b_in_row ^ ((lr & 7) << 4)) >> 1;
  int plane = lr >> 6;
  int f = fb * 128 + half * 64 + (lr & 63);
  int k = kkt * 64 + kl;
  float v = (f < F_BINS) ? (plane ? wcos[f * NFFT + k] : wsin[f * NFFT + k]) : 0.0f;
  *(uint16_t*)(wbt + (size_t)blob * 16384 + lr * 128 + b_in_row) = f2bf(v);
}

// ---- prep: gammatone bf16 [64][1152] ------------------------------------
__global__ __launch_bounds__(256) void build_gb(const float* __restrict__ g,
                                                uint16_t* __restrict__ gb) {
  int i = blockIdx.x * 256 + threadIdx.x;
  int n = i / FPAD;
  int f = i - n * FPAD;
  gb[i] = f2bf(f < F_BINS ? g[n * F_BINS + f] : 0.0f);
}

// ---- reduce: out[b][n][t] = sum_fb slab[fb][n][b*862+t] ------------------
__global__ __launch_bounds__(256) void reduce9(const float* __restrict__ slab,
                                               float* __restrict__ out) {
  int i = blockIdx.x * 256 + threadIdx.x;
  if (i >= J_TOT * NB) return;
  int b = i / (NB * T_FR);
  int rem = i - b * (NB * T_FR);
  int n = rem / T_FR;
  int t = rem - n * T_FR;
  int j = b * T_FR + t;
  float s = 0.f;
#pragma unroll
  for (int fb = 0; fb < NT_F; ++fb)
    s += slab[((size_t)fb * NB + n) * JPAD + j];
  out[i] = s;
}

// ---- main helpers --------------------------------------------------------
__device__ __forceinline__ void load_a(bf16x8 (&dst)[2][2], const char* p,
                                       int k0, int k1) {
  dst[0][0] = *(const bf16x8*)(p + k0);
  dst[0][1] = *(const bf16x8*)(p + k1);
  dst[1][0] = *(const bf16x8*)(p + 2048 + k0);
  dst[1][1] = *(const bf16x8*)(p + 2048 + k1);
}
__device__ __forceinline__ void load_b(bf16x8 (&dst)[4][2], const char* p,
                                       int k0, int k1) {
#pragma unroll
  for (int n = 0; n < 4; ++n) {
    dst[n][0] = *(const bf16x8*)(p + n * 2048 + k0);
    dst[n][1] = *(const bf16x8*)(p + n * 2048 + k1);
  }
}
__device__ __forceinline__ void mfma_pair(f32x4 (*ac)[4],
                                          const bf16x8 (&av)[2][2],
                                          const bf16x8 (&bv)[4][2]) {
#pragma unroll
  for (int m = 0; m < 2; ++m)
#pragma unroll
    for (int n = 0; n < 4; ++n) {
      ac[m][n] = mfma16(av[m][0], bv[n][0], ac[m][n]);
      ac[m][n] = mfma16(av[m][1], bv[n][1], ac[m][n]);
    }
}

// ---- main: 256x256 tile, BK=64, 8 waves, 4-phase, frag-reads pipelined ---
#define AS_OFF(buf)   ((buf) * 65536)
#define BS_OFF(buf)   ((buf) * 65536 + 32768)

template <bool USE_SLAB>
__global__ __launch_bounds__(512, 2) void gammatone_main(
    const char* __restrict__ xbp, const char* __restrict__ wbt,
    const char* __restrict__ gb, float* __restrict__ dst) {
  __shared__ __align__(16) char smem[131072];

  const int tid = threadIdx.x;
  const int w = tid >> 6, l = tid & 63;
  const int lgrp = l >> 4, l15 = l & 15;
  const int wr = w >> 2, wc = w & 3;

  // bijective XCD swizzle (m204), fb-major work order
  const int orig = blockIdx.y * NT_J + blockIdx.x;
  const int xcd = orig & 7, slot = orig >> 3;
  const int q = NWG / 8, r = NWG & 7;            // 121, 4
  const int wkid = (xcd < r ? xcd * (q + 1) : r * (q + 1) + (xcd - r) * q) + slot;
  const int fb = wkid / NT_J;
  const int jb = wkid - fb * NT_J;
  const int j0 = jb * 256;
  const int f0 = fb * 128;

  const int xr = (((tid & 7) << 4)) ^ ((((tid >> 3) & 7)) << 4);
  size_t fbase[2][2];
#pragma unroll
  for (int h = 0; h < 2; ++h)
#pragma unroll
    for (int i = 0; i < 2; ++i) {
      int col = j0 + h * 128 + i * 64 + (tid >> 3);
      if (col > J_TOT - 1) col = J_TOT - 1;
      int b = col / T_FR;
      int t = col - b * T_FR;
      fbase[h][i] = (size_t)b * ROWB + (size_t)t * 1024 + (size_t)xr;
    }

  const size_t wblob0 = (size_t)fb * 32 * 2 * 16384;

#define STAGE_A(kkt, buf) do {                                              \
    const char* g_ = wbt + wblob0 + (size_t)(kkt) * 32768;                  \
    char* d_ = smem + AS_OFF(buf);                                          \
    GLD16(g_ + w * 1024 + l * 16,         d_ + w * 1024 + l * 16);          \
    GLD16(g_ + 8192 + w * 1024 + l * 16,  d_ + 8192 + w * 1024 + l * 16);   \
    GLD16(g_ + 16384 + w * 1024 + l * 16, d_ + 16384 + w * 1024 + l * 16);  \
    GLD16(g_ + 24576 + w * 1024 + l * 16, d_ + 24576 + w * 1024 + l * 16);  \
  } while (0)

#define STAGE_B(kkt, buf, h) do {                                           \
    char* d_ = smem + BS_OFF(buf) + (h) * 16384;                            \
    GLD16(xbp + fbase[h][0] + (size_t)(kkt) * 128, d_ + w * 1024 + l * 16); \
    GLD16(xbp + fbase[h][1] + (size_t)(kkt) * 128, d_ + 8192 + w * 1024 + l * 16); \
  } while (0)

  // per-lane constant LDS read offsets
  const int albase = l15 * 128;
  const int xa = (l15 & 7) << 4;
  const int k0 = (lgrp * 16) ^ xa;
  const int k1 = (64 + lgrp * 16) ^ xa;
  const int jrb = (wc & 1) * 64;

  const char* Ab0 = smem + AS_OFF(0) + wr * 16384 + albase;
  const char* Ab1 = smem + AS_OFF(1) + wr * 16384 + albase;
  const char* Bb0 = smem + BS_OFF(0) + (wc >> 1) * 16384 + jrb * 128 + albase;
  const char* Bb1 = smem + BS_OFF(1) + (wc >> 1) * 16384 + jrb * 128 + albase;

  // prologue staging
  STAGE_A(0, 0);
  STAGE_B(0, 0, 0); STAGE_B(0, 0, 1);
  STAGE_B(1, 1, 0); STAGE_B(1, 1, 1);
  asm volatile("s_waitcnt vmcnt(4)" ::: "memory");
  __builtin_amdgcn_s_barrier();

  f32x4 acc[8][4];
#pragma unroll
  for (int m = 0; m < 8; ++m)
#pragma unroll
    for (int n = 0; n < 4; ++n) acc[m][n] = (f32x4){0.f, 0.f, 0.f, 0.f};

  bf16x8 bvE[4][2], bvO[4][2], av0[2][2], av1[2][2];
  load_b(bvE, Bb0, k0, k1);
  load_a(av0, Ab0, k0, k1);

#define TILE(KK, P, bvC, bvN_, AbC, AbN, BbN) do {                          \
    /* ph0: MFMA pair0; prefetch pair1; stage A(kk+1)->Q */                 \
    load_a(av1, (AbC) + 4096, k0, k1);                                      \
    if ((KK) < 31) STAGE_A((KK) + 1, (P) ^ 1);                              \
    __builtin_amdgcn_s_setprio(1); mfma_pair(&acc[0], av0, bvC);            \
    __builtin_amdgcn_s_setprio(0);                                          \
    __builtin_amdgcn_s_barrier();                                           \
    /* ph1: MFMA pair1; prefetch pair2; stage B(kk+2,h0)->P */              \
    load_a(av0, (AbC) + 8192, k0, k1);                                      \
    if ((KK) < 30) STAGE_B((KK) + 2, P, 0);                                 \
    __builtin_amdgcn_s_setprio(1); mfma_pair(&acc[2], av1, bvC);            \
    __builtin_amdgcn_s_setprio(0);                                          \
    __builtin_amdgcn_s_barrier();                                           \
    /* ph2: MFMA pair2; prefetch pair3; stage B(kk+2,h1)->P */              \
    load_a(av1, (AbC) + 12288, k0, k1);                                     \
    if ((KK) < 30) STAGE_B((KK) + 2, P, 1);                                 \
    __builtin_amdgcn_s_setprio(1); mfma_pair(&acc[4], av0, bvC);            \
    __builtin_amdgcn_s_setprio(0);                                          \
    __builtin_amdgcn_s_barrier();                                           \
    /* ph3: drain kk+1 staging; prefetch next-tile B + pair0; MFMA pair3 */ \
    if ((KK) < 30)       { asm volatile("s_waitcnt vmcnt(4)" ::: "memory"); } \
    else if ((KK) == 30) { asm volatile("s_waitcnt vmcnt(0)" ::: "memory"); } \
    __builtin_amdgcn_s_barrier();                                           \
    if ((KK) < 31) { load_b(bvN_, BbN, k0, k1); load_a(av0, AbN, k0, k1); } \
    __builtin_amdgcn_sched_barrier(0);                                      \
    __builtin_amdgcn_s_setprio(1); mfma_pair(&acc[6], av1, bvC);            \
    __builtin_amdgcn_s_setprio(0);                                          \
    __builtin_amdgcn_s_barrier();                                           \
  } while (0)

  for (int kk = 0; kk < 32; kk += 2) {
    TILE(kk,     0, bvE, bvO, Ab0, Ab1, Bb1);
    TILE(kk + 1, 1, bvO, bvE, Ab1, Ab0, Bb0);
  }

  __syncthreads();
  // spec = s^2 + c^2 -> LDS [j 256][f 128] bf16 swizzled
#pragma unroll
  for (int m = 0; m < 4; ++m) {
    int fi = wr * 64 + m * 16 + lgrp * 4;
#pragma unroll
    for (int n = 0; n < 4; ++n) {
      int j = wc * 64 + n * 16 + l15;
      f32x4 s = acc[m][n], c = acc[m + 4][n];
      uint32_t lo = (uint32_t)f2bf(s.x * s.x + c.x * c.x) |
                    ((uint32_t)f2bf(s.y * s.y + c.y * c.y) << 16);
      uint32_t hi = (uint32_t)f2bf(s.z * s.z + c.z * c.z) |
                    ((uint32_t)f2bf(s.w * s.w + c.w * c.w) << 16);
      int off = j * 256 + ((fi * 2) ^ ((j & 7) << 4));
      *(u32x2*)(smem + off) = (u32x2){lo, hi};
    }
  }
  __syncthreads();

  // second GEMM: out_part[64][256j] = G[64][f0:+128] x spec[128][256]
  f32x4 acc2[4][2];
#pragma unroll
  for (int m = 0; m < 4; ++m) {
    acc2[m][0] = (f32x4){0.f, 0.f, 0.f, 0.f};
    acc2[m][1] = (f32x4){0.f, 0.f, 0.f, 0.f};
  }
  const int jq = w * 32;
#pragma unroll
  for (int ks = 0; ks < 4; ++ks) {
    bf16x8 gf[4], sf[2];
#pragma unroll
    for (int m2 = 0; m2 < 4; ++m2) {
      int grow = m2 * 16 + l15;
      gf[m2] = *(const bf16x8*)(gb + ((size_t)grow * FPAD + f0 + ks * 32 + lgrp * 8) * 2);
    }
#pragma unroll
    for (int nf = 0; nf < 2; ++nf) {
      int j = jq + nf * 16 + l15;
      sf[nf] = *(const bf16x8*)(smem + j * 256 + (((ks * 32 + lgrp * 8) * 2) ^ ((j & 7) << 4)));
    }
#pragma unroll
    for (int m2 = 0; m2 < 4; ++m2)
#pragma unroll
      for (int nf = 0; nf < 2; ++nf)
        acc2[m2][nf] = mfma16(gf[m2], sf[nf], acc2[m2][nf]);
  }

#pragma unroll
  for (int nf = 0; nf < 2; ++nf) {
    int jg = j0 + jq + nf * 16 + l15;
    if (USE_SLAB) {
      float* sl = dst + ((size_t)fb * NB) * JPAD + jg;
#pragma unroll
      for (int m2 = 0; m2 < 4; ++m2)
#pragma unroll
        for (int r2 = 0; r2 < 4; ++r2) {
          int nout = m2 * 16 + lgrp * 4 + r2;
          sl[(size_t)nout * JPAD] = acc2[m2][nf][r2];
        }
    } else if (jg < J_TOT) {
      int b = jg / T_FR;
      int t = jg - b * T_FR;
      float* ob = dst + (size_t)(b * NB) * T_FR + t;
#pragma unroll
      for (int m2 = 0; m2 < 4; ++m2)
#pragma unroll
        for (int r2 = 0; r2 < 4; ++r2) {
          int nout = m2 * 16 + lgrp * 4 + r2;
          atomicAdd(ob + (size_t)nout * T_FR, acc2[m2][nf][r2]);
        }
    }
  }
}

extern "C" void kernel_launch(void* const* d_in, const int* in_sizes, int n_in,
                              void* d_out, int out_size, void* d_ws, size_t ws_size,
                              hipStream_t stream) {
  (void)in_sizes; (void)n_in;
  const float* x    = (const float*)d_in[0];
  const float* wsin = (const float*)d_in[1];
  const float* wcos = (const float*)d_in[2];
  const float* g    = (const float*)d_in[3];
  if (ws_size < (size_t)WS_NEED) return;
  char* ws = (char*)d_ws;
  uint16_t* xbp = (uint16_t*)(ws + XBP_OFF);
  char*     wbt = ws + WBT_OFF;
  uint16_t* gbp = (uint16_t*)(ws + GB_OFF);

  build_xbp<<<(B_SZ * LP) / 256, 256, 0, stream>>>(x, xbp);
  build_wbt<<<(WBT_BYTES / 2) / 256, 256, 0, stream>>>(wsin, wcos, wbt);
  build_gb<<<(NB * FPAD) / 256, 256, 0, stream>>>(g, gbp);

  if (ws_size >= (size_t)WS_BIG) {
    float* slab = (float*)(ws + SLAB_OFF);
    gammatone_main<true><<<dim3(NT_J, NT_F), 512, 0, stream>>>(
        (const char*)xbp, wbt, (const char*)gbp, slab);
    reduce9<<<(J_TOT * NB + 255) / 256, 256, 0, stream>>>(slab, (float*)d_out);
  } else {
    hipMemsetAsync(d_out, 0, (size_t)out_size * sizeof(float), stream);
    gammatone_main<false><<<dim3(NT_J, NT_F), 512, 0, stream>>>(
        (const char*)xbp, wbt, (const char*)gbp, (float*)d_out);
  }
}

// Round 5
// 323.196 us; speedup vs baseline: 1.6178x; 1.6178x over previous
//
#include <hip/hip_runtime.h>
#include <stdint.h>

typedef __attribute__((ext_vector_type(4))) float f32x4;
typedef __attribute__((ext_vector_type(8))) short bf16x8;
typedef __attribute__((ext_vector_type(2))) unsigned int u32x2;

#define B_SZ   32
#define L_AUD  441000
#define PAD_A  1024
#define LP     443048          // L_AUD + 2*PAD_A
#define T_FR   862
#define J_TOT  27584           // B_SZ * T_FR
#define JPAD   27648           // 108 * 256
#define F_BINS 1025
#define NFFT   2048
#define NB     64
#define FPAD   1152            // 9 * 128
#define NT_J   108             // 27648 / 256
#define NT_F   9
#define NWG    (NT_J * NT_F)   // 972
#define ROWB   886096          // LP * 2 bytes per xbp row

#define XBP_OFF   0
#define XBP_BYTES (B_SZ * LP * 2)             // 28,355,072
#define WBT_OFF   XBP_BYTES
#define WBT_BYTES (NT_F * 32 * 2 * 16384)     // 9,437,184
#define GB_OFF    (WBT_OFF + WBT_BYTES)
#define GB_BYTES  (NB * FPAD * 2)             // 147,456
#define WS_NEED   (GB_OFF + GB_BYTES)         // 37,939,712
#define SLAB_OFF  WS_NEED
#define SLAB_BYTES ((size_t)NT_F * NB * JPAD * 4)   // 63,700,992
#define WS_BIG    (SLAB_OFF + SLAB_BYTES)     // 101,640,704

__device__ __forceinline__ uint16_t f2bf(float f) {
  union { float f; uint32_t u; } c; c.f = f;
  uint32_t r = c.u + 0x7FFFu + ((c.u >> 16) & 1u);
  return (uint16_t)(r >> 16);
}

__device__ __forceinline__ f32x4 mfma16(bf16x8 a, bf16x8 b, f32x4 c) {
  return __builtin_amdgcn_mfma_f32_16x16x32_bf16(a, b, c, 0, 0, 0);
}

#define GLD16(g, l) __builtin_amdgcn_global_load_lds( \
    (__attribute__((address_space(1))) void*)(g),     \
    (__attribute__((address_space(3))) void*)(l), 16, 0, 0)

// ---- prep: reflect-padded bf16 audio ------------------------------------
__global__ __launch_bounds__(256) void build_xbp(const float* __restrict__ x,
                                                 uint16_t* __restrict__ xbp) {
  int i = blockIdx.x * 256 + threadIdx.x;
  int b = i / LP;
  int p = i - b * LP;
  int s = p - PAD_A;
  s = s < 0 ? -s : s;
  s = s >= L_AUD ? (2 * L_AUD - 2 - s) : s;
  xbp[i] = f2bf(x[b * L_AUD + s]);
}

// ---- prep: W in FRAG-MAJOR layout for direct global->VGPR A-frag loads ---
// flat elem idx = fb<<19 | kkt<<14 | fm<<10 | s<<9 | l<<3 | e
// lane l of frag (fb,kkt,fm,s) holds A[tr = fm*16 + (l&15)][k = kkt*64 + s*32 + (l>>4)*8 + e]
// tile row tr (0..255): plane = (tr>>6)&1 (0 sin, 1 cos), f = fb*128 + (tr>>7)*64 + (tr&63)
__global__ __launch_bounds__(256) void build_wbt(const float* __restrict__ wsin,
                                                 const float* __restrict__ wcos,
                                                 uint16_t* __restrict__ wbt) {
  int idx = blockIdx.x * 256 + threadIdx.x;
  int e = idx & 7;
  int l = (idx >> 3) & 63;
  int s = (idx >> 9) & 1;
  int fm = (idx >> 10) & 15;
  int kkt = (idx >> 14) & 31;
  int fb = idx >> 19;
  int tr = fm * 16 + (l & 15);
  int k = kkt * 64 + s * 32 + ((l >> 4) << 3) + e;
  int plane = (tr >> 6) & 1;
  int f = fb * 128 + ((tr >> 7) << 6) + (tr & 63);
  float v = (f < F_BINS) ? (plane ? wcos[f * NFFT + k] : wsin[f * NFFT + k]) : 0.0f;
  wbt[idx] = f2bf(v);
}

// ---- prep: gammatone bf16 [64][1152] ------------------------------------
__global__ __launch_bounds__(256) void build_gb(const float* __restrict__ g,
                                                uint16_t* __restrict__ gb) {
  int i = blockIdx.x * 256 + threadIdx.x;
  int n = i / FPAD;
  int f = i - n * FPAD;
  gb[i] = f2bf(f < F_BINS ? g[n * F_BINS + f] : 0.0f);
}

// ---- reduce: out[b][n][t] = sum_fb slab[fb][n][b*862+t] ------------------
__global__ __launch_bounds__(256) void reduce9(const float* __restrict__ slab,
                                               float* __restrict__ out) {
  int i = blockIdx.x * 256 + threadIdx.x;
  if (i >= J_TOT * NB) return;
  int b = i / (NB * T_FR);
  int rem = i - b * (NB * T_FR);
  int n = rem / T_FR;
  int t = rem - n * T_FR;
  int j = b * T_FR + t;
  float s = 0.f;
#pragma unroll
  for (int fb = 0; fb < NT_F; ++fb)
    s += slab[((size_t)fb * NB + n) * JPAD + j];
  out[i] = s;
}

// ---- main helpers --------------------------------------------------------
// load one m-pair of A frags (2 m x 2 ks) straight from global (coalesced 16B/lane)
__device__ __forceinline__ void load_a2(bf16x8 (&d)[2][2], const char* p) {
  d[0][0] = *(const bf16x8*)(p);
  d[0][1] = *(const bf16x8*)(p + 1024);
  d[1][0] = *(const bf16x8*)(p + 2048);
  d[1][1] = *(const bf16x8*)(p + 3072);
}
__device__ __forceinline__ void load_b(bf16x8 (&dst)[4][2], const char* p,
                                       int k0, int k1) {
#pragma unroll
  for (int n = 0; n < 4; ++n) {
    dst[n][0] = *(const bf16x8*)(p + n * 2048 + k0);
    dst[n][1] = *(const bf16x8*)(p + n * 2048 + k1);
  }
}
__device__ __forceinline__ void mfma_pair(f32x4 (*ac)[4],
                                          const bf16x8 (&av)[2][2],
                                          const bf16x8 (&bv)[4][2]) {
#pragma unroll
  for (int m = 0; m < 2; ++m)
#pragma unroll
    for (int n = 0; n < 4; ++n) {
      ac[m][n] = mfma16(av[m][0], bv[n][0], ac[m][n]);
      ac[m][n] = mfma16(av[m][1], bv[n][1], ac[m][n]);
    }
}

// ---- main: 256x256 tile, BK=64, 8 waves; A direct-from-global, B via LDS -
template <bool USE_SLAB>
__global__ __launch_bounds__(512, 2) void gammatone_main(
    const char* __restrict__ xbp, const char* __restrict__ wbt,
    const char* __restrict__ gb, float* __restrict__ dst) {
  __shared__ __align__(16) char smem[65536];   // 2 x 32KB B double-buffer

  const int tid = threadIdx.x;
  const int w = tid >> 6, l = tid & 63;
  const int lgrp = l >> 4, l15 = l & 15;
  const int wr = w >> 2, wc = w & 3;

  // bijective XCD swizzle (m204), fb-major work order
  const int orig = blockIdx.y * NT_J + blockIdx.x;
  const int xcd = orig & 7, slot = orig >> 3;
  const int q = NWG / 8, r = NWG & 7;            // 121, 4
  const int wkid = (xcd < r ? xcd * (q + 1) : r * (q + 1) + (xcd - r) * q) + slot;
  const int fb = wkid / NT_J;
  const int jb = wkid - fb * NT_J;
  const int j0 = jb * 256;
  const int f0 = fb * 128;

  // B staging source bases (pre-swizzled global addr, m173)
  const int xr = (((tid & 7) << 4)) ^ ((((tid >> 3) & 7)) << 4);
  size_t fbase[2][2];
#pragma unroll
  for (int h = 0; h < 2; ++h)
#pragma unroll
    for (int i = 0; i < 2; ++i) {
      int col = j0 + h * 128 + i * 64 + (tid >> 3);
      if (col > J_TOT - 1) col = J_TOT - 1;
      int b = col / T_FR;
      int t = col - b * T_FR;
      fbase[h][i] = (size_t)b * ROWB + (size_t)t * 1024 + (size_t)xr;
    }

#define STAGE_B2(kkt, buf) do {                                             \
    char* d0_ = smem + (buf) * 32768;                                       \
    char* d1_ = smem + (buf) * 32768 + 16384;                               \
    GLD16(xbp + fbase[0][0] + (size_t)(kkt) * 128, d0_ + w * 1024 + l * 16);\
    GLD16(xbp + fbase[0][1] + (size_t)(kkt) * 128, d0_ + 8192 + w * 1024 + l * 16);\
    GLD16(xbp + fbase[1][0] + (size_t)(kkt) * 128, d1_ + w * 1024 + l * 16);\
    GLD16(xbp + fbase[1][1] + (size_t)(kkt) * 128, d1_ + 8192 + w * 1024 + l * 16);\
  } while (0)

  // per-lane constant LDS read offsets for B frags
  const int albase = l15 * 128;
  const int xa = (l15 & 7) << 4;
  const int k0 = (lgrp * 16) ^ xa;
  const int k1 = (64 + lgrp * 16) ^ xa;
  const int jrb = (wc & 1) * 64;
  const char* Bb0 = smem + (wc >> 1) * 16384 + jrb * 128 + albase;
  const char* Bb1 = Bb0 + 32768;

  // A frag-major base for this wave: frags fm = wr*8 + m
  const char* wbt_a = wbt + (size_t)fb * 32 * 32768 + wr * 16384 + (size_t)l * 16;

  // ---- prologue: stage B(0)->buf0, B(1)->buf1; first B frags + A pair0 ---
  STAGE_B2(0, 0);
  STAGE_B2(1, 1);
  asm volatile("s_waitcnt vmcnt(0)" ::: "memory");
  __builtin_amdgcn_s_barrier();

  f32x4 acc[8][4];
#pragma unroll
  for (int m = 0; m < 8; ++m)
#pragma unroll
    for (int n = 0; n < 4; ++n) acc[m][n] = (f32x4){0.f, 0.f, 0.f, 0.f};

  bf16x8 bvA[4][2], bvB[4][2], av0[2][2], av1[2][2];
  load_b(bvA, Bb0, k0, k1);
  load_a2(av0, wbt_a);
  asm volatile("s_waitcnt lgkmcnt(0)" ::: "memory");
  __builtin_amdgcn_s_barrier();   // buf0 reads done before tile0 restages it

#define SP1 __builtin_amdgcn_s_setprio(1)
#define SP0 __builtin_amdgcn_s_setprio(0)

  // Per tile: 1 barrier + 1 lgkm(0). vmcnt correctness: staging glds are
  // older than this tile's A-reads, which the compiler waits on before the
  // MFMAs -> ordered vmcnt counter guarantees staging drained by tile end.
#define TILE(KK, bvC, bvN, BbN, STG, NXT) do {                              \
    const char* aT = wbt_a + (size_t)(KK) * 32768;                          \
    if (STG) STAGE_B2((KK) + 2, (KK) & 1);                                  \
    load_a2(av1, aT + 2 * 2048);                                            \
    SP1; mfma_pair(&acc[0], av0, bvC); SP0;                                 \
    load_a2(av0, aT + 4 * 2048);                                            \
    SP1; mfma_pair(&acc[2], av1, bvC); SP0;                                 \
    load_a2(av1, aT + 6 * 2048);                                            \
    if (NXT) load_b(bvN, BbN, k0, k1);                                      \
    SP1; mfma_pair(&acc[4], av0, bvC); SP0;                                 \
    if (NXT) load_a2(av0, wbt_a + (size_t)((KK) + 1) * 32768);              \
    SP1; mfma_pair(&acc[6], av1, bvC); SP0;                                 \
    asm volatile("s_waitcnt lgkmcnt(0)" ::: "memory");                      \
    __builtin_amdgcn_s_barrier();                                           \
  } while (0)

  for (int kk = 0; kk < 30; kk += 2) {
    TILE(kk,     bvA, bvB, Bb1, 1, 1);
    TILE(kk + 1, bvB, bvA, Bb0, 1, 1);
  }
  TILE(30, bvA, bvB, Bb1, 0, 1);
  TILE(31, bvB, bvA, Bb0, 0, 0);

  __syncthreads();
  // spec = s^2 + c^2 -> LDS [j 256][f 128] bf16 swizzled
#pragma unroll
  for (int m = 0; m < 4; ++m) {
    int fi = wr * 64 + m * 16 + lgrp * 4;
#pragma unroll
    for (int n = 0; n < 4; ++n) {
      int j = wc * 64 + n * 16 + l15;
      f32x4 s = acc[m][n], c = acc[m + 4][n];
      uint32_t lo = (uint32_t)f2bf(s.x * s.x + c.x * c.x) |
                    ((uint32_t)f2bf(s.y * s.y + c.y * c.y) << 16);
      uint32_t hi = (uint32_t)f2bf(s.z * s.z + c.z * c.z) |
                    ((uint32_t)f2bf(s.w * s.w + c.w * c.w) << 16);
      int off = j * 256 + ((fi * 2) ^ ((j & 7) << 4));
      *(u32x2*)(smem + off) = (u32x2){lo, hi};
    }
  }
  __syncthreads();

  // second GEMM: out_part[64][256j] = G[64][f0:+128] x spec[128][256]
  f32x4 acc2[4][2];
#pragma unroll
  for (int m = 0; m < 4; ++m) {
    acc2[m][0] = (f32x4){0.f, 0.f, 0.f, 0.f};
    acc2[m][1] = (f32x4){0.f, 0.f, 0.f, 0.f};
  }
  const int jq = w * 32;
#pragma unroll
  for (int ks = 0; ks < 4; ++ks) {
    bf16x8 gf[4], sf[2];
#pragma unroll
    for (int m2 = 0; m2 < 4; ++m2) {
      int grow = m2 * 16 + l15;
      gf[m2] = *(const bf16x8*)(gb + ((size_t)grow * FPAD + f0 + ks * 32 + lgrp * 8) * 2);
    }
#pragma unroll
    for (int nf = 0; nf < 2; ++nf) {
      int j = jq + nf * 16 + l15;
      sf[nf] = *(const bf16x8*)(smem + j * 256 + (((ks * 32 + lgrp * 8) * 2) ^ ((j & 7) << 4)));
    }
#pragma unroll
    for (int m2 = 0; m2 < 4; ++m2)
#pragma unroll
      for (int nf = 0; nf < 2; ++nf)
        acc2[m2][nf] = mfma16(gf[m2], sf[nf], acc2[m2][nf]);
  }

#pragma unroll
  for (int nf = 0; nf < 2; ++nf) {
    int jg = j0 + jq + nf * 16 + l15;
    if (USE_SLAB) {
      float* sl = dst + ((size_t)fb * NB) * JPAD + jg;
#pragma unroll
      for (int m2 = 0; m2 < 4; ++m2)
#pragma unroll
        for (int r2 = 0; r2 < 4; ++r2) {
          int nout = m2 * 16 + lgrp * 4 + r2;
          sl[(size_t)nout * JPAD] = acc2[m2][nf][r2];
        }
    } else if (jg < J_TOT) {
      int b = jg / T_FR;
      int t = jg - b * T_FR;
      float* ob = dst + (size_t)(b * NB) * T_FR + t;
#pragma unroll
      for (int m2 = 0; m2 < 4; ++m2)
#pragma unroll
        for (int r2 = 0; r2 < 4; ++r2) {
          int nout = m2 * 16 + lgrp * 4 + r2;
          atomicAdd(ob + (size_t)nout * T_FR, acc2[m2][nf][r2]);
        }
    }
  }
}

extern "C" void kernel_launch(void* const* d_in, const int* in_sizes, int n_in,
                              void* d_out, int out_size, void* d_ws, size_t ws_size,
                              hipStream_t stream) {
  (void)in_sizes; (void)n_in;
  const float* x    = (const float*)d_in[0];
  const float* wsin = (const float*)d_in[1];
  const float* wcos = (const float*)d_in[2];
  const float* g    = (const float*)d_in[3];
  if (ws_size < (size_t)WS_NEED) return;
  char* ws = (char*)d_ws;
  uint16_t* xbp = (uint16_t*)(ws + XBP_OFF);
  uint16_t* wbt = (uint16_t*)(ws + WBT_OFF);
  uint16_t* gbp = (uint16_t*)(ws + GB_OFF);

  build_xbp<<<(B_SZ * LP) / 256, 256, 0, stream>>>(x, xbp);
  build_wbt<<<(WBT_BYTES / 2) / 256, 256, 0, stream>>>(wsin, wcos, wbt);
  build_gb<<<(NB * FPAD) / 256, 256, 0, stream>>>(g, gbp);

  if (ws_size >= (size_t)WS_BIG) {
    float* slab = (float*)(ws + SLAB_OFF);
    gammatone_main<true><<<dim3(NT_J, NT_F), 512, 0, stream>>>(
        (const char*)xbp, (const char*)wbt, (const char*)gbp, slab);
    reduce9<<<(J_TOT * NB + 255) / 256, 256, 0, stream>>>(slab, (float*)d_out);
  } else {
    hipMemsetAsync(d_out, 0, (size_t)out_size * sizeof(float), stream);
    gammatone_main<false><<<dim3(NT_J, NT_F), 512, 0, stream>>>(
        (const char*)xbp, (const char*)wbt, (const char*)gbp, (float*)d_out);
  }
}

// Round 6
// 272.162 us; speedup vs baseline: 1.9211x; 1.1875x over previous
//
#include <hip/hip_runtime.h>
#include <stdint.h>

typedef __attribute__((ext_vector_type(4))) float f32x4;
typedef __attribute__((ext_vector_type(8))) short bf16x8;
typedef __attribute__((ext_vector_type(8))) unsigned short u16x8;
typedef __attribute__((ext_vector_type(2))) unsigned int u32x2;

#define B_SZ   32
#define L_AUD  441000
#define PAD_A  1024
#define LP     443048          // L_AUD + 2*PAD_A
#define T_FR   862
#define J_TOT  27584           // B_SZ * T_FR
#define JPAD   27648           // 108 * 256
#define F_BINS 1025
#define NFFT   2048
#define NB     64
#define FPAD   1152            // 9 * 128
#define NT_J   108
#define NT_F   9
#define NWG    (NT_J * NT_F)   // 972
#define ROWB   886096          // LP * 2 bytes per xbp row

// ---- fold-path ws layout -------------------------------------------------
#define W2_OFF     0
#define W2_BYTES   (NT_F * 32 * 16384)            // 4,718,592 (A blobs, K=1024)
#define GB2_OFF    W2_BYTES
#define GB2_BYTES  (NB * FPAD * 2)                // 147,456
#define UB_OFF     (GB2_OFF + GB2_BYTES)          // 4,866,048
#define UB_BYTES   ((size_t)JPAD * 2048 * 2)      // 113,246,208 (u+/u- bf16)
#define WS_FOLD    (UB_OFF + UB_BYTES)            // 118,112,256
#define SLAB_BYTES ((size_t)NT_F * NB * JPAD * 4) // 63,700,992
#define WS_FOLD_SLAB (WS_FOLD + SLAB_BYTES)       // 181,813,248

// ---- fallback (round-5) ws layout ---------------------------------------
#define FB_XBP_OFF   0
#define FB_XBP_BYTES (B_SZ * LP * 2)              // 28,355,072
#define FB_WBT_OFF   FB_XBP_BYTES
#define FB_WBT_BYTES (NT_F * 32 * 2 * 16384)      // 9,437,184
#define FB_GB_OFF    (FB_WBT_OFF + FB_WBT_BYTES)
#define FB_WS_NEED   (FB_GB_OFF + GB2_BYTES)      // 37,939,712
#define FB_SLAB_OFF  FB_WS_NEED
#define FB_WS_BIG    ((size_t)FB_SLAB_OFF + SLAB_BYTES) // 101,640,704

__device__ __forceinline__ uint16_t f2bf(float f) {
  union { float f; uint32_t u; } c; c.f = f;
  uint32_t r = c.u + 0x7FFFu + ((c.u >> 16) & 1u);
  return (uint16_t)(r >> 16);
}

__device__ __forceinline__ f32x4 mfma16(bf16x8 a, bf16x8 b, f32x4 c) {
  return __builtin_amdgcn_mfma_f32_16x16x32_bf16(a, b, c, 0, 0, 0);
}

#define GLD16(g, l) __builtin_amdgcn_global_load_lds( \
    (__attribute__((address_space(1))) void*)(g),     \
    (__attribute__((address_space(3))) void*)(l), 16, 0, 0)

__device__ __forceinline__ int refl(int p) {   // padded coord -> sample idx
  int s = p - PAD_A;
  s = s < 0 ? -s : s;
  s = s >= L_AUD ? (2 * L_AUD - 2 - s) : s;
  return s;
}

// ==== shared preps ========================================================

// gammatone bf16 [64][1152]
__global__ __launch_bounds__(256) void build_gb(const float* __restrict__ g,
                                                uint16_t* __restrict__ gb) {
  int i = blockIdx.x * 256 + threadIdx.x;
  int n = i / FPAD;
  int f = i - n * FPAD;
  gb[i] = f2bf(f < F_BINS ? g[n * F_BINS + f] : 0.0f);
}

// out[b][n][t] = sum_fb slab[fb][n][b*862+t]
__global__ __launch_bounds__(256) void reduce9(const float* __restrict__ slab,
                                               float* __restrict__ out) {
  int i = blockIdx.x * 256 + threadIdx.x;
  if (i >= J_TOT * NB) return;
  int b = i / (NB * T_FR);
  int rem = i - b * (NB * T_FR);
  int n = rem / T_FR;
  int t = rem - n * T_FR;
  int j = b * T_FR + t;
  float s = 0.f;
#pragma unroll
  for (int fb = 0; fb < NT_F; ++fb)
    s += slab[((size_t)fb * NB + n) * JPAD + j];
  out[i] = s;
}

// ==== fold-path preps =====================================================

// A blobs, K'=1024: blob (fb,kkt32) = [256 rows][32 k] bf16 linear (16 KB).
// rows 0..127 = cos (A+ = wcos), 128..255 = sin (A- = wsin); f = fb*128+(row&127)
// slot m = kkt*32+k; m==0 is the folded center term: A[f][0] = w*[f][1024].
__global__ __launch_bounds__(256) void build_wbt2(const float* __restrict__ wsin,
                                                  const float* __restrict__ wcos,
                                                  uint16_t* __restrict__ wbt) {
  int idx = blockIdx.x * 256 + threadIdx.x;   // 9*32*256*32 = 2,359,296
  int k = idx & 31;
  int row = (idx >> 5) & 255;
  int kkt = (idx >> 13) & 31;
  int fb = idx >> 18;
  int plane = row >> 7;                        // 0 cos, 1 sin
  int f = fb * 128 + (row & 127);
  int m = kkt * 32 + k;
  float v = 0.f;
  if (f < F_BINS) {
    int mm = (m == 0) ? 1024 : m;
    v = plane ? wsin[(size_t)f * NFFT + mm] : wcos[(size_t)f * NFFT + mm];
  }
  wbt[idx] = f2bf(v);
}

// folded frames: ub[j][sign][1024] bf16. sign0 = x[m]+x[2048-m], sign1 = diff.
// slot 0: u+ = x(center), u- = 0. reflect-pad inline from raw x.
__global__ __launch_bounds__(256) void build_ub(const float* __restrict__ x,
                                                uint16_t* __restrict__ ub) {
  int idx = blockIdx.x * 256 + threadIdx.x;   // JPAD*128
  int jg = idx >> 7;
  int m0 = (idx & 127) << 3;
  u16x8 vp = (u16x8)0, vm = (u16x8)0;
  if (jg < J_TOT) {
    int b = jg / T_FR, t = jg - b * T_FR;
    int c = t * 512;
    const float* xb = x + (size_t)b * L_AUD;
#pragma unroll
    for (int i = 0; i < 8; ++i) {
      int m = m0 + i;
      float xf = xb[refl(c + (m == 0 ? 1024 : m))];
      float xr = xb[refl(c + 2048 - m)];
      float up, um;
      if (m == 0) { up = xf; um = 0.f; }
      else        { up = xf + xr; um = xf - xr; }
      vp[i] = f2bf(up); vm[i] = f2bf(um);
    }
  }
  *(u16x8*)(ub + (size_t)jg * 2048 + m0) = vp;
  *(u16x8*)(ub + (size_t)jg * 2048 + 1024 + m0) = vm;
}

// ==== fold main: 256rows x 256j, K'=1024, BK=32, tri-buffer, 1 bar/tile ===
template <bool USE_SLAB>
__global__ __launch_bounds__(512, 2) void gammatone_fold(
    const char* __restrict__ ub, const char* __restrict__ wbt2,
    const char* __restrict__ gb, float* __restrict__ dst) {
  __shared__ __align__(16) char smem[147456];   // 3 x 48KB {A16K, B+16K, B-16K}

  const int tid = threadIdx.x;
  const int w = tid >> 6, l = tid & 63;
  const int lgrp = l >> 4, l15 = l & 15;
  const int fh = w >> 2, jq = w & 3;            // f-half, j-quarter

  // bijective XCD chunking, j-major order (fb fastest): per-XCD ub reuse in L2
  const int orig = blockIdx.x;
  const int xcd = orig & 7, slot = orig >> 3;
  const int q = NWG / 8, r = NWG & 7;           // 121, 4
  const int wkid = (xcd < r ? xcd * (q + 1) : r * (q + 1) + (xcd - r) * q) + slot;
  const int jb = wkid / NT_F;
  const int fb = wkid - jb * NT_F;
  const int j0 = jb * 256;
  const int f0 = fb * 128;

  // staging: wave w stages A rows [w*32,+32) (2 glds) and sign s=w>>2,
  // B rows [q4*64,+64) (4 glds). All linear (64B rows -> no swizzle needed).
  const int ssn = w >> 2, q4 = w & 3;
  const int aoff_sta = w * 2048 + l * 16;
  const int boff_sta = 16384 + ssn * 16384 + q4 * 4096 + l * 16;
  const char* bsrc[4];
#pragma unroll
  for (int i = 0; i < 4; ++i) {
    int col = j0 + q4 * 64 + i * 16 + (l >> 2);   // <= JPAD-1 always
    bsrc[i] = ub + (size_t)col * 4096 + ssn * 2048 + (l & 3) * 16;
  }
  const char* wbtA = wbt2 + (size_t)fb * 524288;

#define STAGEF(kkt, off) do {                                               \
    const char* ga_ = wbtA + (size_t)(kkt) * 16384 + aoff_sta;              \
    GLD16(ga_,        smem + (off) + aoff_sta);                             \
    GLD16(ga_ + 1024, smem + (off) + aoff_sta + 1024);                      \
    GLD16(bsrc[0] + (size_t)(kkt) * 64, smem + (off) + boff_sta);           \
    GLD16(bsrc[1] + (size_t)(kkt) * 64, smem + (off) + boff_sta + 1024);    \
    GLD16(bsrc[2] + (size_t)(kkt) * 64, smem + (off) + boff_sta + 2048);    \
    GLD16(bsrc[3] + (size_t)(kkt) * 64, smem + (off) + boff_sta + 3072);    \
  } while (0)

  // per-lane read offsets (64B rows, conflict-optimal unswizzled)
  int aoff[8], bpo[4], bmo[4];
#pragma unroll
  for (int m = 0; m < 8; ++m)
    aoff[m] = ((m >> 2) * 128 + fh * 64 + (m & 3) * 16 + l15) * 64 + lgrp * 16;
#pragma unroll
  for (int n = 0; n < 4; ++n) {
    bpo[n] = 16384 + (jq * 64 + n * 16 + l15) * 64 + lgrp * 16;
    bmo[n] = bpo[n] + 16384;
  }

  // prologue: tiles 0,1 -> buf0,buf1
  STAGEF(0, 0);
  STAGEF(1, 49152);
  asm volatile("s_waitcnt vmcnt(6)" ::: "memory");
  asm volatile("s_barrier" ::: "memory");

  f32x4 acc[8][4];
#pragma unroll
  for (int m = 0; m < 8; ++m)
#pragma unroll
    for (int n = 0; n < 4; ++n) acc[m][n] = (f32x4){0.f, 0.f, 0.f, 0.f};

  unsigned b0 = 0, b1 = 49152, b2 = 98304;
  for (int kk = 0; kk < 32; ++kk) {
    bf16x8 av[8], bp[4], bm[4];
#pragma unroll
    for (int m = 0; m < 8; ++m) av[m] = *(const bf16x8*)(smem + b0 + aoff[m]);
#pragma unroll
    for (int n = 0; n < 4; ++n) {
      bp[n] = *(const bf16x8*)(smem + b0 + bpo[n]);
      bm[n] = *(const bf16x8*)(smem + b0 + bmo[n]);
    }
    if (kk < 30) STAGEF(kk + 2, b2);
    __builtin_amdgcn_s_setprio(1);
#pragma unroll
    for (int m = 0; m < 4; ++m)
#pragma unroll
      for (int n = 0; n < 4; ++n) {
        acc[m][n]     = mfma16(av[m],     bp[n], acc[m][n]);
        acc[m + 4][n] = mfma16(av[m + 4], bm[n], acc[m + 4][n]);
      }
    __builtin_amdgcn_s_setprio(0);
    // counted drain: stage(kk+1) landed for everyone before next tile reads it
    if (kk < 30)       asm volatile("s_waitcnt vmcnt(6)" ::: "memory");
    else if (kk == 30) asm volatile("s_waitcnt vmcnt(0)" ::: "memory");
    asm volatile("s_barrier" ::: "memory");
    unsigned t = b0; b0 = b1; b1 = b2; b2 = t;
  }

  // spec = s^2 + c^2 -> LDS [256 j][128 f] bf16, swizzled (256B rows)
#pragma unroll
  for (int m = 0; m < 4; ++m) {
    int fi = fh * 64 + m * 16 + lgrp * 4;
#pragma unroll
    for (int n = 0; n < 4; ++n) {
      int j = jq * 64 + n * 16 + l15;
      f32x4 c = acc[m][n], s = acc[m + 4][n];
      uint32_t lo = (uint32_t)f2bf(s.x * s.x + c.x * c.x) |
                    ((uint32_t)f2bf(s.y * s.y + c.y * c.y) << 16);
      uint32_t hi = (uint32_t)f2bf(s.z * s.z + c.z * c.z) |
                    ((uint32_t)f2bf(s.w * s.w + c.w * c.w) << 16);
      int off = j * 256 + ((fi * 2) ^ ((j & 7) << 4));
      *(u32x2*)(smem + off) = (u32x2){lo, hi};
    }
  }
  __syncthreads();

  // second GEMM: out_part[64][256j] = G[64][f0:+128] x spec[128][256]
  f32x4 acc2[4][2];
#pragma unroll
  for (int m = 0; m < 4; ++m) {
    acc2[m][0] = (f32x4){0.f, 0.f, 0.f, 0.f};
    acc2[m][1] = (f32x4){0.f, 0.f, 0.f, 0.f};
  }
  const int jw = w * 32;
#pragma unroll
  for (int ks = 0; ks < 4; ++ks) {
    bf16x8 gf[4], sf[2];
#pragma unroll
    for (int m2 = 0; m2 < 4; ++m2) {
      int grow = m2 * 16 + l15;
      gf[m2] = *(const bf16x8*)(gb + ((size_t)grow * FPAD + f0 + ks * 32 + lgrp * 8) * 2);
    }
#pragma unroll
    for (int nf = 0; nf < 2; ++nf) {
      int j = jw + nf * 16 + l15;
      sf[nf] = *(const bf16x8*)(smem + j * 256 + (((ks * 32 + lgrp * 8) * 2) ^ ((j & 7) << 4)));
    }
#pragma unroll
    for (int m2 = 0; m2 < 4; ++m2)
#pragma unroll
      for (int nf = 0; nf < 2; ++nf)
        acc2[m2][nf] = mfma16(gf[m2], sf[nf], acc2[m2][nf]);
  }

#pragma unroll
  for (int nf = 0; nf < 2; ++nf) {
    int jg = j0 + jw + nf * 16 + l15;
    if (USE_SLAB) {
      float* sl = dst + ((size_t)fb * NB) * JPAD + jg;
#pragma unroll
      for (int m2 = 0; m2 < 4; ++m2)
#pragma unroll
        for (int r2 = 0; r2 < 4; ++r2) {
          int nout = m2 * 16 + lgrp * 4 + r2;
          sl[(size_t)nout * JPAD] = acc2[m2][nf][r2];
        }
    } else if (jg < J_TOT) {
      int b = jg / T_FR;
      int t = jg - b * T_FR;
      float* ob = dst + (size_t)(b * NB) * T_FR + t;
#pragma unroll
      for (int m2 = 0; m2 < 4; ++m2)
#pragma unroll
        for (int r2 = 0; r2 < 4; ++r2) {
          int nout = m2 * 16 + lgrp * 4 + r2;
          atomicAdd(ob + (size_t)nout * T_FR, acc2[m2][nf][r2]);
        }
    }
  }
}

// ==== fallback path (round-5 kernels, verbatim) ===========================

__global__ __launch_bounds__(256) void build_xbp(const float* __restrict__ x,
                                                 uint16_t* __restrict__ xbp) {
  int i = blockIdx.x * 256 + threadIdx.x;
  int b = i / LP;
  int p = i - b * LP;
  xbp[i] = f2bf(x[b * L_AUD + refl(p)]);
}

__global__ __launch_bounds__(256) void build_wbtf(const float* __restrict__ wsin,
                                                  const float* __restrict__ wcos,
                                                  uint16_t* __restrict__ wbt) {
  int idx = blockIdx.x * 256 + threadIdx.x;
  int e = idx & 7;
  int l = (idx >> 3) & 63;
  int s = (idx >> 9) & 1;
  int fm = (idx >> 10) & 15;
  int kkt = (idx >> 14) & 31;
  int fb = idx >> 19;
  int tr = fm * 16 + (l & 15);
  int k = kkt * 64 + s * 32 + ((l >> 4) << 3) + e;
  int plane = (tr >> 6) & 1;
  int f = fb * 128 + ((tr >> 7) << 6) + (tr & 63);
  float v = (f < F_BINS) ? (plane ? wcos[f * NFFT + k] : wsin[f * NFFT + k]) : 0.0f;
  wbt[idx] = f2bf(v);
}

__device__ __forceinline__ void load_a2(bf16x8 (&d)[2][2], const char* p) {
  d[0][0] = *(const bf16x8*)(p);
  d[0][1] = *(const bf16x8*)(p + 1024);
  d[1][0] = *(const bf16x8*)(p + 2048);
  d[1][1] = *(const bf16x8*)(p + 3072);
}
__device__ __forceinline__ void load_b4(bf16x8 (&dst)[4][2], const char* p,
                                        int k0, int k1) {
#pragma unroll
  for (int n = 0; n < 4; ++n) {
    dst[n][0] = *(const bf16x8*)(p + n * 2048 + k0);
    dst[n][1] = *(const bf16x8*)(p + n * 2048 + k1);
  }
}
__device__ __forceinline__ void mfma_pair(f32x4 (*ac)[4],
                                          const bf16x8 (&av)[2][2],
                                          const bf16x8 (&bv)[4][2]) {
#pragma unroll
  for (int m = 0; m < 2; ++m)
#pragma unroll
    for (int n = 0; n < 4; ++n) {
      ac[m][n] = mfma16(av[m][0], bv[n][0], ac[m][n]);
      ac[m][n] = mfma16(av[m][1], bv[n][1], ac[m][n]);
    }
}

template <bool USE_SLAB>
__global__ __launch_bounds__(512, 2) void gammatone_fb(
    const char* __restrict__ xbp, const char* __restrict__ wbt,
    const char* __restrict__ gb, float* __restrict__ dst) {
  __shared__ __align__(16) char smem[65536];

  const int tid = threadIdx.x;
  const int w = tid >> 6, l = tid & 63;
  const int lgrp = l >> 4, l15 = l & 15;
  const int wr = w >> 2, wc = w & 3;

  const int orig = blockIdx.y * NT_J + blockIdx.x;
  const int xcd = orig & 7, slot = orig >> 3;
  const int q = NWG / 8, r = NWG & 7;
  const int wkid = (xcd < r ? xcd * (q + 1) : r * (q + 1) + (xcd - r) * q) + slot;
  const int fb = wkid / NT_J;
  const int jb = wkid - fb * NT_J;
  const int j0 = jb * 256;
  const int f0 = fb * 128;

  const int xr = (((tid & 7) << 4)) ^ ((((tid >> 3) & 7)) << 4);
  size_t fbase[2][2];
#pragma unroll
  for (int h = 0; h < 2; ++h)
#pragma unroll
    for (int i = 0; i < 2; ++i) {
      int col = j0 + h * 128 + i * 64 + (tid >> 3);
      if (col > J_TOT - 1) col = J_TOT - 1;
      int b = col / T_FR;
      int t = col - b * T_FR;
      fbase[h][i] = (size_t)b * ROWB + (size_t)t * 1024 + (size_t)xr;
    }

#define STAGE_B2(kkt, buf) do {                                             \
    char* d0_ = smem + (buf) * 32768;                                       \
    char* d1_ = smem + (buf) * 32768 + 16384;                               \
    GLD16(xbp + fbase[0][0] + (size_t)(kkt) * 128, d0_ + w * 1024 + l * 16);\
    GLD16(xbp + fbase[0][1] + (size_t)(kkt) * 128, d0_ + 8192 + w * 1024 + l * 16);\
    GLD16(xbp + fbase[1][0] + (size_t)(kkt) * 128, d1_ + w * 1024 + l * 16);\
    GLD16(xbp + fbase[1][1] + (size_t)(kkt) * 128, d1_ + 8192 + w * 1024 + l * 16);\
  } while (0)

  const int albase = l15 * 128;
  const int xa = (l15 & 7) << 4;
  const int k0 = (lgrp * 16) ^ xa;
  const int k1 = (64 + lgrp * 16) ^ xa;
  const int jrb = (wc & 1) * 64;
  const char* Bb0 = smem + (wc >> 1) * 16384 + jrb * 128 + albase;
  const char* Bb1 = Bb0 + 32768;
  const char* wbt_a = wbt + (size_t)fb * 32 * 32768 + wr * 16384 + (size_t)l * 16;

  STAGE_B2(0, 0);
  STAGE_B2(1, 1);
  asm volatile("s_waitcnt vmcnt(0)" ::: "memory");
  __builtin_amdgcn_s_barrier();

  f32x4 acc[8][4];
#pragma unroll
  for (int m = 0; m < 8; ++m)
#pragma unroll
    for (int n = 0; n < 4; ++n) acc[m][n] = (f32x4){0.f, 0.f, 0.f, 0.f};

  bf16x8 bvA[4][2], bvB[4][2], av0[2][2], av1[2][2];
  load_b4(bvA, Bb0, k0, k1);
  load_a2(av0, wbt_a);
  asm volatile("s_waitcnt lgkmcnt(0)" ::: "memory");
  __builtin_amdgcn_s_barrier();

#define SP1 __builtin_amdgcn_s_setprio(1)
#define SP0 __builtin_amdgcn_s_setprio(0)

#define TILEFB(KK, bvC, bvN, BbN, STG, NXT) do {                            \
    const char* aT = wbt_a + (size_t)(KK) * 32768;                          \
    if (STG) STAGE_B2((KK) + 2, (KK) & 1);                                  \
    load_a2(av1, aT + 2 * 2048);                                            \
    SP1; mfma_pair(&acc[0], av0, bvC); SP0;                                 \
    load_a2(av0, aT + 4 * 2048);                                            \
    SP1; mfma_pair(&acc[2], av1, bvC); SP0;                                 \
    load_a2(av1, aT + 6 * 2048);                                            \
    if (NXT) load_b4(bvN, BbN, k0, k1);                                     \
    SP1; mfma_pair(&acc[4], av0, bvC); SP0;                                 \
    if (NXT) load_a2(av0, wbt_a + (size_t)((KK) + 1) * 32768);              \
    SP1; mfma_pair(&acc[6], av1, bvC); SP0;                                 \
    asm volatile("s_waitcnt lgkmcnt(0)" ::: "memory");                      \
    __builtin_amdgcn_s_barrier();                                           \
  } while (0)

  for (int kk = 0; kk < 30; kk += 2) {
    TILEFB(kk,     bvA, bvB, Bb1, 1, 1);
    TILEFB(kk + 1, bvB, bvA, Bb0, 1, 1);
  }
  TILEFB(30, bvA, bvB, Bb1, 0, 1);
  TILEFB(31, bvB, bvA, Bb0, 0, 0);

  __syncthreads();
#pragma unroll
  for (int m = 0; m < 4; ++m) {
    int fi = wr * 64 + m * 16 + lgrp * 4;
#pragma unroll
    for (int n = 0; n < 4; ++n) {
      int j = wc * 64 + n * 16 + l15;
      f32x4 s = acc[m][n], c = acc[m + 4][n];
      uint32_t lo = (uint32_t)f2bf(s.x * s.x + c.x * c.x) |
                    ((uint32_t)f2bf(s.y * s.y + c.y * c.y) << 16);
      uint32_t hi = (uint32_t)f2bf(s.z * s.z + c.z * c.z) |
                    ((uint32_t)f2bf(s.w * s.w + c.w * c.w) << 16);
      int off = j * 256 + ((fi * 2) ^ ((j & 7) << 4));
      *(u32x2*)(smem + off) = (u32x2){lo, hi};
    }
  }
  __syncthreads();

  f32x4 acc2[4][2];
#pragma unroll
  for (int m = 0; m < 4; ++m) {
    acc2[m][0] = (f32x4){0.f, 0.f, 0.f, 0.f};
    acc2[m][1] = (f32x4){0.f, 0.f, 0.f, 0.f};
  }
  const int jw = w * 32;
#pragma unroll
  for (int ks = 0; ks < 4; ++ks) {
    bf16x8 gf[4], sf[2];
#pragma unroll
    for (int m2 = 0; m2 < 4; ++m2) {
      int grow = m2 * 16 + l15;
      gf[m2] = *(const bf16x8*)(gb + ((size_t)grow * FPAD + f0 + ks * 32 + lgrp * 8) * 2);
    }
#pragma unroll
    for (int nf = 0; nf < 2; ++nf) {
      int j = jw + nf * 16 + l15;
      sf[nf] = *(const bf16x8*)(smem + j * 256 + (((ks * 32 + lgrp * 8) * 2) ^ ((j & 7) << 4)));
    }
#pragma unroll
    for (int m2 = 0; m2 < 4; ++m2)
#pragma unroll
      for (int nf = 0; nf < 2; ++nf)
        acc2[m2][nf] = mfma16(gf[m2], sf[nf], acc2[m2][nf]);
  }

#pragma unroll
  for (int nf = 0; nf < 2; ++nf) {
    int jg = j0 + jw + nf * 16 + l15;
    if (USE_SLAB) {
      float* sl = dst + ((size_t)fb * NB) * JPAD + jg;
#pragma unroll
      for (int m2 = 0; m2 < 4; ++m2)
#pragma unroll
        for (int r2 = 0; r2 < 4; ++r2) {
          int nout = m2 * 16 + lgrp * 4 + r2;
          sl[(size_t)nout * JPAD] = acc2[m2][nf][r2];
        }
    } else if (jg < J_TOT) {
      int b = jg / T_FR;
      int t = jg - b * T_FR;
      float* ob = dst + (size_t)(b * NB) * T_FR + t;
#pragma unroll
      for (int m2 = 0; m2 < 4; ++m2)
#pragma unroll
        for (int r2 = 0; r2 < 4; ++r2) {
          int nout = m2 * 16 + lgrp * 4 + r2;
          atomicAdd(ob + (size_t)nout * T_FR, acc2[m2][nf][r2]);
        }
    }
  }
}

// ==== launcher ============================================================
extern "C" void kernel_launch(void* const* d_in, const int* in_sizes, int n_in,
                              void* d_out, int out_size, void* d_ws, size_t ws_size,
                              hipStream_t stream) {
  (void)in_sizes; (void)n_in;
  const float* x    = (const float*)d_in[0];
  const float* wsin = (const float*)d_in[1];
  const float* wcos = (const float*)d_in[2];
  const float* g    = (const float*)d_in[3];
  char* ws = (char*)d_ws;

  if (ws_size >= (size_t)WS_FOLD) {
    uint16_t* wbt2 = (uint16_t*)(ws + W2_OFF);
    uint16_t* gbp  = (uint16_t*)(ws + GB2_OFF);
    uint16_t* ub   = (uint16_t*)(ws + UB_OFF);
    build_wbt2<<<(W2_BYTES / 2) / 256, 256, 0, stream>>>(wsin, wcos, wbt2);
    build_gb<<<(NB * FPAD) / 256, 256, 0, stream>>>(g, gbp);
    build_ub<<<(JPAD * 128) / 256, 256, 0, stream>>>(x, ub);
    if (ws_size >= (size_t)WS_FOLD_SLAB) {
      float* slab = (float*)(ws + WS_FOLD);
      gammatone_fold<true><<<NWG, 512, 0, stream>>>(
          (const char*)ub, (const char*)wbt2, (const char*)gbp, slab);
      reduce9<<<(J_TOT * NB + 255) / 256, 256, 0, stream>>>(slab, (float*)d_out);
    } else {
      hipMemsetAsync(d_out, 0, (size_t)out_size * sizeof(float), stream);
      gammatone_fold<false><<<NWG, 512, 0, stream>>>(
          (const char*)ub, (const char*)wbt2, (const char*)gbp, (float*)d_out);
    }
    return;
  }

  // fallback: round-5 path
  if (ws_size < (size_t)FB_WS_NEED) return;
  uint16_t* xbp = (uint16_t*)(ws + FB_XBP_OFF);
  uint16_t* wbt = (uint16_t*)(ws + FB_WBT_OFF);
  uint16_t* gbp = (uint16_t*)(ws + FB_GB_OFF);
  build_xbp<<<(B_SZ * LP) / 256, 256, 0, stream>>>(x, xbp);
  build_wbtf<<<(FB_WBT_BYTES / 2) / 256, 256, 0, stream>>>(wsin, wcos, wbt);
  build_gb<<<(NB * FPAD) / 256, 256, 0, stream>>>(g, gbp);
  if (ws_size >= (size_t)FB_WS_BIG) {
    float* slab = (float*)(ws + FB_SLAB_OFF);
    gammatone_fb<true><<<dim3(NT_J, NT_F), 512, 0, stream>>>(
        (const char*)xbp, (const char*)wbt, (const char*)gbp, slab);
    reduce9<<<(J_TOT * NB + 255) / 256, 256, 0, stream>>>(slab, (float*)d_out);
  } else {
    hipMemsetAsync(d_out, 0, (size_t)out_size * sizeof(float), stream);
    gammatone_fb<false><<<dim3(NT_J, NT_F), 512, 0, stream>>>(
        (const char*)xbp, (const char*)wbt, (const char*)gbp, (float*)d_out);
  }
}

// Round 7
// 215.750 us; speedup vs baseline: 2.4234x; 1.2615x over previous
//
#include <hip/hip_runtime.h>
#include <stdint.h>

typedef __attribute__((ext_vector_type(4))) float f32x4;
typedef __attribute__((ext_vector_type(8))) short bf16x8;
typedef __attribute__((ext_vector_type(8))) unsigned short u16x8;
typedef __attribute__((ext_vector_type(2))) unsigned int u32x2;

#define B_SZ   32
#define L_AUD  441000
#define PAD_A  1024
#define LP     443048          // L_AUD + 2*PAD_A
#define T_FR   862
#define J_TOT  27584           // B_SZ * T_FR
#define JPAD   27648           // 108 * 256
#define F_BINS 1025
#define NFFT   2048
#define NB     64
#define FPAD   1152            // 9 * 128
#define NT_J   108
#define NT_F   9
#define NWG    (NT_J * NT_F)   // 972
#define ROWB   886096          // LP * 2 bytes per xbp row

// ---- fold-path ws layout -------------------------------------------------
#define W2_OFF     0
#define W2_BYTES   (NT_F * 32 * 16384)            // 4,718,592 (A blobs, K=1024)
#define GB2_OFF    W2_BYTES
#define GB2_BYTES  (NB * FPAD * 2)                // 147,456
#define UB_OFF     (GB2_OFF + GB2_BYTES)          // 4,866,048
#define UB_BYTES   ((size_t)JPAD * 2048 * 2)      // 113,246,208 (u+/u- bf16)
#define WS_FOLD    (UB_OFF + UB_BYTES)            // 118,112,256
#define SLAB_BYTES ((size_t)NT_F * NB * JPAD * 4) // 63,700,992
#define WS_FOLD_SLAB (WS_FOLD + SLAB_BYTES)       // 181,813,248

// ---- fallback (round-5) ws layout ---------------------------------------
#define FB_XBP_OFF   0
#define FB_XBP_BYTES (B_SZ * LP * 2)              // 28,355,072
#define FB_WBT_OFF   FB_XBP_BYTES
#define FB_WBT_BYTES (NT_F * 32 * 2 * 16384)      // 9,437,184
#define FB_GB_OFF    (FB_WBT_OFF + FB_WBT_BYTES)
#define FB_WS_NEED   (FB_GB_OFF + GB2_BYTES)      // 37,939,712
#define FB_SLAB_OFF  FB_WS_NEED
#define FB_WS_BIG    ((size_t)FB_SLAB_OFF + SLAB_BYTES) // 101,640,704

__device__ __forceinline__ uint16_t f2bf(float f) {
  union { float f; uint32_t u; } c; c.f = f;
  uint32_t r = c.u + 0x7FFFu + ((c.u >> 16) & 1u);
  return (uint16_t)(r >> 16);
}

__device__ __forceinline__ f32x4 mfma16(bf16x8 a, bf16x8 b, f32x4 c) {
  return __builtin_amdgcn_mfma_f32_16x16x32_bf16(a, b, c, 0, 0, 0);
}

#define GLD16(g, l) __builtin_amdgcn_global_load_lds( \
    (__attribute__((address_space(1))) void*)(g),     \
    (__attribute__((address_space(3))) void*)(l), 16, 0, 0)

__device__ __forceinline__ int refl(int p) {   // padded coord -> sample idx
  int s = p - PAD_A;
  s = s < 0 ? -s : s;
  s = s >= L_AUD ? (2 * L_AUD - 2 - s) : s;
  return s;
}

// ==== shared preps ========================================================

__global__ __launch_bounds__(256) void build_gb(const float* __restrict__ g,
                                                uint16_t* __restrict__ gb) {
  int i = blockIdx.x * 256 + threadIdx.x;
  int n = i / FPAD;
  int f = i - n * FPAD;
  gb[i] = f2bf(f < F_BINS ? g[n * F_BINS + f] : 0.0f);
}

__global__ __launch_bounds__(256) void reduce9(const float* __restrict__ slab,
                                               float* __restrict__ out) {
  int i = blockIdx.x * 256 + threadIdx.x;
  if (i >= J_TOT * NB) return;
  int b = i / (NB * T_FR);
  int rem = i - b * (NB * T_FR);
  int n = rem / T_FR;
  int t = rem - n * T_FR;
  int j = b * T_FR + t;
  float s = 0.f;
#pragma unroll
  for (int fb = 0; fb < NT_F; ++fb)
    s += slab[((size_t)fb * NB + n) * JPAD + j];
  out[i] = s;
}

// ==== fold-path preps =====================================================

// A blobs, K'=1024, PAIR-SWIZZLED: blob (fb,kkt) = 16KB, 128 rowpairs x 128B.
// byte(r,k) = (r>>1)*128 + (((k>>3)|((r&1)<<2)) ^ ((r>>1)&7))*16 + (k&7)*2
// rows 0..127 = cos, 128..255 = sin; f = fb*128+(r&127); m = kkt*32+k (m==0 -> w[f][1024])
__global__ __launch_bounds__(256) void build_wbt2(const float* __restrict__ wsin,
                                                  const float* __restrict__ wcos,
                                                  uint16_t* __restrict__ wbt) {
  int idx = blockIdx.x * 256 + threadIdx.x;   // 2,359,296 bf16 elements
  int e = idx & 7;
  int s = (idx >> 3) & 7;
  int jp = (idx >> 6) & 127;
  int kkt = (idx >> 13) & 31;
  int fb = idx >> 18;
  int v = s ^ (jp & 7);
  int r = jp * 2 + (v >> 2);
  int k = (v & 3) * 8 + e;
  int plane = r >> 7;                          // 0 cos, 1 sin
  int f = fb * 128 + (r & 127);
  int m = kkt * 32 + k;
  float val = 0.f;
  if (f < F_BINS) {
    int mm = (m == 0) ? 1024 : m;
    val = plane ? wsin[(size_t)f * NFFT + mm] : wcos[(size_t)f * NFFT + mm];
  }
  wbt[idx] = f2bf(val);
}

// folded frames: ub[j][sign][1024] bf16 (layout unchanged; fold staging
// pre-swizzles its per-lane SOURCE address). One 128-thread block per frame,
// window staged to LDS via coalesced float4.
__global__ __launch_bounds__(128) void build_ub(const float* __restrict__ x,
                                                uint16_t* __restrict__ ub) {
  __shared__ float xs[2048];
  int jg = blockIdx.x;
  int tid = threadIdx.x;
  uint16_t* outp = ub + (size_t)jg * 2048;
  if (jg >= J_TOT) {
    u16x8 z = (u16x8)0;
    *(u16x8*)(outp + tid * 8) = z;
    *(u16x8*)(outp + 1024 + tid * 8) = z;
    return;
  }
  int b = jg / T_FR, t = jg - b * T_FR;
  int c = t * 512;
  const float* xb = x + (size_t)b * L_AUD;
  if (t >= 2 && t <= 859) {
    const float4* src = (const float4*)(xb + c - PAD_A);
    float4* dl = (float4*)xs;
#pragma unroll
    for (int i = 0; i < 4; ++i) dl[tid * 4 + i] = src[tid * 4 + i];
  } else {
#pragma unroll
    for (int i = 0; i < 16; ++i) xs[tid * 16 + i] = xb[refl(c + tid * 16 + i)];
  }
  __syncthreads();
  int m0 = tid * 8;
  u16x8 vp, vm;
#pragma unroll
  for (int i = 0; i < 8; ++i) {
    int m = m0 + i;
    if (m == 0) { vp[i] = f2bf(xs[1024]); vm[i] = 0; }
    else {
      float a = xs[m], r = xs[2048 - m];
      vp[i] = f2bf(a + r);
      vm[i] = f2bf(a - r);
    }
  }
  *(u16x8*)(outp + m0) = vp;
  *(u16x8*)(outp + 1024 + m0) = vm;
}

// ==== fold main: 256rows x 256j, K'=1024, BK=32, tri-buffer, 1 bar/tile ===
// LDS tiles pair-swizzled (2-way bank alias = free). A blob pre-swizzled in
// global; B staged with inverse-swizzled per-lane source (m173).
template <bool USE_SLAB>
__global__ __launch_bounds__(512, 2) void gammatone_fold(
    const char* __restrict__ ub, const char* __restrict__ wbt2,
    const char* __restrict__ gb, float* __restrict__ dst) {
  __shared__ __align__(16) char smem[147456];   // 3 x 48KB {A16K, B+16K, B-16K}

  const int tid = threadIdx.x;
  const int w = tid >> 6, l = tid & 63;
  const int lgrp = l >> 4, l15 = l & 15;
  const int fh = w >> 2, jq = w & 3;            // f-half, j-quarter

  // bijective XCD chunking, j-major order (fb fastest)
  const int orig = blockIdx.x;
  const int xcd = orig & 7, slot = orig >> 3;
  const int q = NWG / 8, r = NWG & 7;           // 121, 4
  const int wkid = (xcd < r ? xcd * (q + 1) : r * (q + 1) + (xcd - r) * q) + slot;
  const int jb = wkid / NT_F;
  const int fb = wkid - jb * NT_F;
  const int j0 = jb * 256;
  const int f0 = fb * 128;

  // staging: wave w stages A bytes [w*2048,+2048) (2 glds) and sign ssn=w>>2,
  // B quarter q4=w&3 (4 glds). LDS dest linear; B source inverse-swizzled:
  // dest L in sign-tile -> jp=L>>7, s=(L>>4)&7; v=s^(jp&7); j=jp*2+(v>>2); ks=v&3
  const int ssn = w >> 2, q4 = w & 3;
  const int aoff_sta = w * 2048 + l * 16;
  const int boff_sta = 16384 + ssn * 16384 + q4 * 4096 + l * 16;
  const int vsw = (l & 7) ^ (l >> 3);
  const char* bsrc[4];
#pragma unroll
  for (int i = 0; i < 4; ++i) {
    int col = j0 + q4 * 64 + i * 16 + (l >> 3) * 2 + (vsw >> 2);
    bsrc[i] = ub + (size_t)col * 4096 + ssn * 2048 + (vsw & 3) * 16;
  }
  const char* wbtA = wbt2 + (size_t)fb * 524288;

#define STAGEF(kkt, off) do {                                               \
    const char* ga_ = wbtA + (size_t)(kkt) * 16384 + aoff_sta;              \
    GLD16(ga_,        smem + (off) + aoff_sta);                             \
    GLD16(ga_ + 1024, smem + (off) + aoff_sta + 1024);                      \
    GLD16(bsrc[0] + (size_t)(kkt) * 64, smem + (off) + boff_sta);           \
    GLD16(bsrc[1] + (size_t)(kkt) * 64, smem + (off) + boff_sta + 1024);    \
    GLD16(bsrc[2] + (size_t)(kkt) * 64, smem + (off) + boff_sta + 2048);    \
    GLD16(bsrc[3] + (size_t)(kkt) * 64, smem + (off) + boff_sta + 3072);    \
  } while (0)

  // swizzled per-lane read offsets: row r, k-slot lgrp ->
  // (r>>1)*128 + ((lgrp|((r&1)<<2)) ^ ((r>>1)&7))*16 ; (r>>1)&7 == l15>>1 here
  const int slb = ((lgrp | ((l15 & 1) << 2)) ^ (l15 >> 1)) << 4;
  int aoff[8], bpo[4], bmo[4];
#pragma unroll
  for (int m = 0; m < 8; ++m)
    aoff[m] = ((m >> 2) * 64 + fh * 32 + (m & 3) * 8 + (l15 >> 1)) * 128 + slb;
#pragma unroll
  for (int n = 0; n < 4; ++n) {
    bpo[n] = 16384 + (jq * 32 + n * 8 + (l15 >> 1)) * 128 + slb;
    bmo[n] = bpo[n] + 16384;
  }

  // prologue: tiles 0,1 -> buf0,buf1
  STAGEF(0, 0);
  STAGEF(1, 49152);
  asm volatile("s_waitcnt vmcnt(6)" ::: "memory");
  asm volatile("s_barrier" ::: "memory");

  f32x4 acc[8][4];
#pragma unroll
  for (int m = 0; m < 8; ++m)
#pragma unroll
    for (int n = 0; n < 4; ++n) acc[m][n] = (f32x4){0.f, 0.f, 0.f, 0.f};

  unsigned b0 = 0, b1 = 49152, b2 = 98304;
  for (int kk = 0; kk < 32; ++kk) {
    bf16x8 av[8], bp[4], bm[4];
#pragma unroll
    for (int m = 0; m < 8; ++m) av[m] = *(const bf16x8*)(smem + b0 + aoff[m]);
#pragma unroll
    for (int n = 0; n < 4; ++n) {
      bp[n] = *(const bf16x8*)(smem + b0 + bpo[n]);
      bm[n] = *(const bf16x8*)(smem + b0 + bmo[n]);
    }
    if (kk < 30) STAGEF(kk + 2, b2);
    __builtin_amdgcn_s_setprio(1);
#pragma unroll
    for (int m = 0; m < 4; ++m)
#pragma unroll
      for (int n = 0; n < 4; ++n) {
        acc[m][n]     = mfma16(av[m],     bp[n], acc[m][n]);
        acc[m + 4][n] = mfma16(av[m + 4], bm[n], acc[m + 4][n]);
      }
    __builtin_amdgcn_s_setprio(0);
    if (kk < 30)       asm volatile("s_waitcnt vmcnt(6)" ::: "memory");
    else if (kk == 30) asm volatile("s_waitcnt vmcnt(0)" ::: "memory");
    asm volatile("s_barrier" ::: "memory");
    unsigned t = b0; b0 = b1; b1 = b2; b2 = t;
  }

  // spec = s^2 + c^2 -> LDS [256 j][128 f] bf16, swizzled (256B rows)
#pragma unroll
  for (int m = 0; m < 4; ++m) {
    int fi = fh * 64 + m * 16 + lgrp * 4;
#pragma unroll
    for (int n = 0; n < 4; ++n) {
      int j = jq * 64 + n * 16 + l15;
      f32x4 c = acc[m][n], s = acc[m + 4][n];
      uint32_t lo = (uint32_t)f2bf(s.x * s.x + c.x * c.x) |
                    ((uint32_t)f2bf(s.y * s.y + c.y * c.y) << 16);
      uint32_t hi = (uint32_t)f2bf(s.z * s.z + c.z * c.z) |
                    ((uint32_t)f2bf(s.w * s.w + c.w * c.w) << 16);
      int off = j * 256 + ((fi * 2) ^ ((j & 7) << 4));
      *(u32x2*)(smem + off) = (u32x2){lo, hi};
    }
  }
  __syncthreads();

  // second GEMM: out_part[64][256j] = G[64][f0:+128] x spec[128][256]
  f32x4 acc2[4][2];
#pragma unroll
  for (int m = 0; m < 4; ++m) {
    acc2[m][0] = (f32x4){0.f, 0.f, 0.f, 0.f};
    acc2[m][1] = (f32x4){0.f, 0.f, 0.f, 0.f};
  }
  const int jw = w * 32;
#pragma unroll
  for (int ks = 0; ks < 4; ++ks) {
    bf16x8 gf[4], sf[2];
#pragma unroll
    for (int m2 = 0; m2 < 4; ++m2) {
      int grow = m2 * 16 + l15;
      gf[m2] = *(const bf16x8*)(gb + ((size_t)grow * FPAD + f0 + ks * 32 + lgrp * 8) * 2);
    }
#pragma unroll
    for (int nf = 0; nf < 2; ++nf) {
      int j = jw + nf * 16 + l15;
      sf[nf] = *(const bf16x8*)(smem + j * 256 + (((ks * 32 + lgrp * 8) * 2) ^ ((j & 7) << 4)));
    }
#pragma unroll
    for (int m2 = 0; m2 < 4; ++m2)
#pragma unroll
      for (int nf = 0; nf < 2; ++nf)
        acc2[m2][nf] = mfma16(gf[m2], sf[nf], acc2[m2][nf]);
  }

#pragma unroll
  for (int nf = 0; nf < 2; ++nf) {
    int jg = j0 + jw + nf * 16 + l15;
    if (USE_SLAB) {
      float* sl = dst + ((size_t)fb * NB) * JPAD + jg;
#pragma unroll
      for (int m2 = 0; m2 < 4; ++m2)
#pragma unroll
        for (int r2 = 0; r2 < 4; ++r2) {
          int nout = m2 * 16 + lgrp * 4 + r2;
          sl[(size_t)nout * JPAD] = acc2[m2][nf][r2];
        }
    } else if (jg < J_TOT) {
      int b = jg / T_FR;
      int t = jg - b * T_FR;
      float* ob = dst + (size_t)(b * NB) * T_FR + t;
#pragma unroll
      for (int m2 = 0; m2 < 4; ++m2)
#pragma unroll
        for (int r2 = 0; r2 < 4; ++r2) {
          int nout = m2 * 16 + lgrp * 4 + r2;
          atomicAdd(ob + (size_t)nout * T_FR, acc2[m2][nf][r2]);
        }
    }
  }
}

// ==== fallback path (round-5 kernels, verbatim) ===========================

__global__ __launch_bounds__(256) void build_xbp(const float* __restrict__ x,
                                                 uint16_t* __restrict__ xbp) {
  int i = blockIdx.x * 256 + threadIdx.x;
  int b = i / LP;
  int p = i - b * LP;
  xbp[i] = f2bf(x[b * L_AUD + refl(p)]);
}

__global__ __launch_bounds__(256) void build_wbtf(const float* __restrict__ wsin,
                                                  const float* __restrict__ wcos,
                                                  uint16_t* __restrict__ wbt) {
  int idx = blockIdx.x * 256 + threadIdx.x;
  int e = idx & 7;
  int l = (idx >> 3) & 63;
  int s = (idx >> 9) & 1;
  int fm = (idx >> 10) & 15;
  int kkt = (idx >> 14) & 31;
  int fb = idx >> 19;
  int tr = fm * 16 + (l & 15);
  int k = kkt * 64 + s * 32 + ((l >> 4) << 3) + e;
  int plane = (tr >> 6) & 1;
  int f = fb * 128 + ((tr >> 7) << 6) + (tr & 63);
  float v = (f < F_BINS) ? (plane ? wcos[f * NFFT + k] : wsin[f * NFFT + k]) : 0.0f;
  wbt[idx] = f2bf(v);
}

__device__ __forceinline__ void load_a2(bf16x8 (&d)[2][2], const char* p) {
  d[0][0] = *(const bf16x8*)(p);
  d[0][1] = *(const bf16x8*)(p + 1024);
  d[1][0] = *(const bf16x8*)(p + 2048);
  d[1][1] = *(const bf16x8*)(p + 3072);
}
__device__ __forceinline__ void load_b4(bf16x8 (&dst)[4][2], const char* p,
                                        int k0, int k1) {
#pragma unroll
  for (int n = 0; n < 4; ++n) {
    dst[n][0] = *(const bf16x8*)(p + n * 2048 + k0);
    dst[n][1] = *(const bf16x8*)(p + n * 2048 + k1);
  }
}
__device__ __forceinline__ void mfma_pair(f32x4 (*ac)[4],
                                          const bf16x8 (&av)[2][2],
                                          const bf16x8 (&bv)[4][2]) {
#pragma unroll
  for (int m = 0; m < 2; ++m)
#pragma unroll
    for (int n = 0; n < 4; ++n) {
      ac[m][n] = mfma16(av[m][0], bv[n][0], ac[m][n]);
      ac[m][n] = mfma16(av[m][1], bv[n][1], ac[m][n]);
    }
}

template <bool USE_SLAB>
__global__ __launch_bounds__(512, 2) void gammatone_fb(
    const char* __restrict__ xbp, const char* __restrict__ wbt,
    const char* __restrict__ gb, float* __restrict__ dst) {
  __shared__ __align__(16) char smem[65536];

  const int tid = threadIdx.x;
  const int w = tid >> 6, l = tid & 63;
  const int lgrp = l >> 4, l15 = l & 15;
  const int wr = w >> 2, wc = w & 3;

  const int orig = blockIdx.y * NT_J + blockIdx.x;
  const int xcd = orig & 7, slot = orig >> 3;
  const int q = NWG / 8, r = NWG & 7;
  const int wkid = (xcd < r ? xcd * (q + 1) : r * (q + 1) + (xcd - r) * q) + slot;
  const int fb = wkid / NT_J;
  const int jb = wkid - fb * NT_J;
  const int j0 = jb * 256;
  const int f0 = fb * 128;

  const int xr = (((tid & 7) << 4)) ^ ((((tid >> 3) & 7)) << 4);
  size_t fbase[2][2];
#pragma unroll
  for (int h = 0; h < 2; ++h)
#pragma unroll
    for (int i = 0; i < 2; ++i) {
      int col = j0 + h * 128 + i * 64 + (tid >> 3);
      if (col > J_TOT - 1) col = J_TOT - 1;
      int b = col / T_FR;
      int t = col - b * T_FR;
      fbase[h][i] = (size_t)b * ROWB + (size_t)t * 1024 + (size_t)xr;
    }

#define STAGE_B2(kkt, buf) do {                                             \
    char* d0_ = smem + (buf) * 32768;                                       \
    char* d1_ = smem + (buf) * 32768 + 16384;                               \
    GLD16(xbp + fbase[0][0] + (size_t)(kkt) * 128, d0_ + w * 1024 + l * 16);\
    GLD16(xbp + fbase[0][1] + (size_t)(kkt) * 128, d0_ + 8192 + w * 1024 + l * 16);\
    GLD16(xbp + fbase[1][0] + (size_t)(kkt) * 128, d1_ + w * 1024 + l * 16);\
    GLD16(xbp + fbase[1][1] + (size_t)(kkt) * 128, d1_ + 8192 + w * 1024 + l * 16);\
  } while (0)

  const int albase = l15 * 128;
  const int xa = (l15 & 7) << 4;
  const int k0 = (lgrp * 16) ^ xa;
  const int k1 = (64 + lgrp * 16) ^ xa;
  const int jrb = (wc & 1) * 64;
  const char* Bb0 = smem + (wc >> 1) * 16384 + jrb * 128 + albase;
  const char* Bb1 = Bb0 + 32768;
  const char* wbt_a = wbt + (size_t)fb * 32 * 32768 + wr * 16384 + (size_t)l * 16;

  STAGE_B2(0, 0);
  STAGE_B2(1, 1);
  asm volatile("s_waitcnt vmcnt(0)" ::: "memory");
  __builtin_amdgcn_s_barrier();

  f32x4 acc[8][4];
#pragma unroll
  for (int m = 0; m < 8; ++m)
#pragma unroll
    for (int n = 0; n < 4; ++n) acc[m][n] = (f32x4){0.f, 0.f, 0.f, 0.f};

  bf16x8 bvA[4][2], bvB[4][2], av0[2][2], av1[2][2];
  load_b4(bvA, Bb0, k0, k1);
  load_a2(av0, wbt_a);
  asm volatile("s_waitcnt lgkmcnt(0)" ::: "memory");
  __builtin_amdgcn_s_barrier();

#define SP1 __builtin_amdgcn_s_setprio(1)
#define SP0 __builtin_amdgcn_s_setprio(0)

#define TILEFB(KK, bvC, bvN, BbN, STG, NXT) do {                            \
    const char* aT = wbt_a + (size_t)(KK) * 32768;                          \
    if (STG) STAGE_B2((KK) + 2, (KK) & 1);                                  \
    load_a2(av1, aT + 2 * 2048);                                            \
    SP1; mfma_pair(&acc[0], av0, bvC); SP0;                                 \
    load_a2(av0, aT + 4 * 2048);                                            \
    SP1; mfma_pair(&acc[2], av1, bvC); SP0;                                 \
    load_a2(av1, aT + 6 * 2048);                                            \
    if (NXT) load_b4(bvN, BbN, k0, k1);                                     \
    SP1; mfma_pair(&acc[4], av0, bvC); SP0;                                 \
    if (NXT) load_a2(av0, wbt_a + (size_t)((KK) + 1) * 32768);              \
    SP1; mfma_pair(&acc[6], av1, bvC); SP0;                                 \
    asm volatile("s_waitcnt lgkmcnt(0)" ::: "memory");                      \
    __builtin_amdgcn_s_barrier();                                           \
  } while (0)

  for (int kk = 0; kk < 30; kk += 2) {
    TILEFB(kk,     bvA, bvB, Bb1, 1, 1);
    TILEFB(kk + 1, bvB, bvA, Bb0, 1, 1);
  }
  TILEFB(30, bvA, bvB, Bb1, 0, 1);
  TILEFB(31, bvB, bvA, Bb0, 0, 0);

  __syncthreads();
#pragma unroll
  for (int m = 0; m < 4; ++m) {
    int fi = wr * 64 + m * 16 + lgrp * 4;
#pragma unroll
    for (int n = 0; n < 4; ++n) {
      int j = wc * 64 + n * 16 + l15;
      f32x4 s = acc[m][n], c = acc[m + 4][n];
      uint32_t lo = (uint32_t)f2bf(s.x * s.x + c.x * c.x) |
                    ((uint32_t)f2bf(s.y * s.y + c.y * c.y) << 16);
      uint32_t hi = (uint32_t)f2bf(s.z * s.z + c.z * c.z) |
                    ((uint32_t)f2bf(s.w * s.w + c.w * c.w) << 16);
      int off = j * 256 + ((fi * 2) ^ ((j & 7) << 4));
      *(u32x2*)(smem + off) = (u32x2){lo, hi};
    }
  }
  __syncthreads();

  f32x4 acc2[4][2];
#pragma unroll
  for (int m = 0; m < 4; ++m) {
    acc2[m][0] = (f32x4){0.f, 0.f, 0.f, 0.f};
    acc2[m][1] = (f32x4){0.f, 0.f, 0.f, 0.f};
  }
  const int jw = w * 32;
#pragma unroll
  for (int ks = 0; ks < 4; ++ks) {
    bf16x8 gf[4], sf[2];
#pragma unroll
    for (int m2 = 0; m2 < 4; ++m2) {
      int grow = m2 * 16 + l15;
      gf[m2] = *(const bf16x8*)(gb + ((size_t)grow * FPAD + f0 + ks * 32 + lgrp * 8) * 2);
    }
#pragma unroll
    for (int nf = 0; nf < 2; ++nf) {
      int j = jw + nf * 16 + l15;
      sf[nf] = *(const bf16x8*)(smem + j * 256 + (((ks * 32 + lgrp * 8) * 2) ^ ((j & 7) << 4)));
    }
#pragma unroll
    for (int m2 = 0; m2 < 4; ++m2)
#pragma unroll
      for (int nf = 0; nf < 2; ++nf)
        acc2[m2][nf] = mfma16(gf[m2], sf[nf], acc2[m2][nf]);
  }

#pragma unroll
  for (int nf = 0; nf < 2; ++nf) {
    int jg = j0 + jw + nf * 16 + l15;
    if (USE_SLAB) {
      float* sl = dst + ((size_t)fb * NB) * JPAD + jg;
#pragma unroll
      for (int m2 = 0; m2 < 4; ++m2)
#pragma unroll
        for (int r2 = 0; r2 < 4; ++r2) {
          int nout = m2 * 16 + lgrp * 4 + r2;
          sl[(size_t)nout * JPAD] = acc2[m2][nf][r2];
        }
    } else if (jg < J_TOT) {
      int b = jg / T_FR;
      int t = jg - b * T_FR;
      float* ob = dst + (size_t)(b * NB) * T_FR + t;
#pragma unroll
      for (int m2 = 0; m2 < 4; ++m2)
#pragma unroll
        for (int r2 = 0; r2 < 4; ++r2) {
          int nout = m2 * 16 + lgrp * 4 + r2;
          atomicAdd(ob + (size_t)nout * T_FR, acc2[m2][nf][r2]);
        }
    }
  }
}

// ==== launcher ============================================================
extern "C" void kernel_launch(void* const* d_in, const int* in_sizes, int n_in,
                              void* d_out, int out_size, void* d_ws, size_t ws_size,
                              hipStream_t stream) {
  (void)in_sizes; (void)n_in;
  const float* x    = (const float*)d_in[0];
  const float* wsin = (const float*)d_in[1];
  const float* wcos = (const float*)d_in[2];
  const float* g    = (const float*)d_in[3];
  char* ws = (char*)d_ws;

  if (ws_size >= (size_t)WS_FOLD) {
    uint16_t* wbt2 = (uint16_t*)(ws + W2_OFF);
    uint16_t* gbp  = (uint16_t*)(ws + GB2_OFF);
    uint16_t* ub   = (uint16_t*)(ws + UB_OFF);
    build_wbt2<<<(W2_BYTES / 2) / 256, 256, 0, stream>>>(wsin, wcos, wbt2);
    build_gb<<<(NB * FPAD) / 256, 256, 0, stream>>>(g, gbp);
    build_ub<<<JPAD, 128, 0, stream>>>(x, ub);
    if (ws_size >= (size_t)WS_FOLD_SLAB) {
      float* slab = (float*)(ws + WS_FOLD);
      gammatone_fold<true><<<NWG, 512, 0, stream>>>(
          (const char*)ub, (const char*)wbt2, (const char*)gbp, slab);
      reduce9<<<(J_TOT * NB + 255) / 256, 256, 0, stream>>>(slab, (float*)d_out);
    } else {
      hipMemsetAsync(d_out, 0, (size_t)out_size * sizeof(float), stream);
      gammatone_fold<false><<<NWG, 512, 0, stream>>>(
          (const char*)ub, (const char*)wbt2, (const char*)gbp, (float*)d_out);
    }
    return;
  }

  // fallback: round-5 path
  if (ws_size < (size_t)FB_WS_NEED) return;
  uint16_t* xbp = (uint16_t*)(ws + FB_XBP_OFF);
  uint16_t* wbt = (uint16_t*)(ws + FB_WBT_OFF);
  uint16_t* gbp = (uint16_t*)(ws + FB_GB_OFF);
  build_xbp<<<(B_SZ * LP) / 256, 256, 0, stream>>>(x, xbp);
  build_wbtf<<<(FB_WBT_BYTES / 2) / 256, 256, 0, stream>>>(wsin, wcos, wbt);
  build_gb<<<(NB * FPAD) / 256, 256, 0, stream>>>(g, gbp);
  if (ws_size >= (size_t)FB_WS_BIG) {
    float* slab = (float*)(ws + FB_SLAB_OFF);
    gammatone_fb<true><<<dim3(NT_J, NT_F), 512, 0, stream>>>(
        (const char*)xbp, (const char*)wbt, (const char*)gbp, slab);
    reduce9<<<(J_TOT * NB + 255) / 256, 256, 0, stream>>>(slab, (float*)d_out);
  } else {
    hipMemsetAsync(d_out, 0, (size_t)out_size * sizeof(float), stream);
    gammatone_fb<false><<<dim3(NT_J, NT_F), 512, 0, stream>>>(
        (const char*)xbp, (const char*)wbt, (const char*)gbp, (float*)d_out);
  }
}